// Round 14
// baseline (197.029 us; speedup 1.0000x reference)
//
#include <hip/hip_runtime.h>
#include <hip/hip_bf16.h>
#include <math.h>
#include <stdint.h>

#define DIM   64
#define KNB   16
#define QKVW  192

typedef short bf16x8 __attribute__((ext_vector_type(8)));
typedef float f32x4  __attribute__((ext_vector_type(4)));

__device__ __forceinline__ short f2bf_s(float x) {
    return (short)__builtin_bit_cast(unsigned short, __float2bfloat16(x));
}
__device__ __forceinline__ float bf2f(uint16_t u) {
    uint32_t v = ((uint32_t)u) << 16;
    return __builtin_bit_cast(float, v);
}
// XOR-swizzled byte offset for the [64][80]-uint16 rel/vrel buffers:
// row*160 + (chbyte ^ ((row&7)<<4)). Bijective within the row; keeps 16B
// alignment for chbyte multiples of 16. Kills the 8-way b16 scatter conflicts.
__device__ __forceinline__ int rv_off(int row, int chbyte) {
    return row * 160 + (chbyte ^ ((row & 7) << 4));
}

// ---------------------------------------------------------------------------
// prep: qkv projection (blocks < nqkvb) + weight prepack (remaining blocks).
// qkv -> bf16 [N][192] (q|k|v). Fragment: non-K = lane&15, K = 32kt+8(lane>>4)+j.
// ---------------------------------------------------------------------------
__global__ __launch_bounds__(256) void prep_kernel(
    const float* __restrict__ x, const float* __restrict__ wqkv,
    const float* __restrict__ am_w1, const float* __restrict__ am_w2,
    const float* __restrict__ pm_w2,
    uint16_t* __restrict__ qkvp, uint16_t* __restrict__ w1p,
    uint16_t* __restrict__ w2p, uint16_t* __restrict__ pw2p,
    int n, int nqkvb)
{
    const int tid = threadIdx.x;
    if (blockIdx.x < nqkvb) {
        const int c  = tid & 63;
        const int rq = tid >> 6;
        const int r0 = blockIdx.x * 16;
        __shared__ float s_x[16][64];
#pragma unroll
        for (int t = 0; t < 4; ++t) {
            const int row = r0 + rq + 4 * t;
            s_x[rq + 4 * t][c] = (row < n) ? x[(size_t)row * 64 + c] : 0.f;
        }
        __syncthreads();
        float aq[4] = {0, 0, 0, 0}, ak[4] = {0, 0, 0, 0}, av[4] = {0, 0, 0, 0};
        for (int d = 0; d < 64; ++d) {
            const float w0 = wqkv[d * QKVW + c];
            const float w1 = wqkv[d * QKVW + 64 + c];
            const float w2 = wqkv[d * QKVW + 128 + c];
#pragma unroll
            for (int t = 0; t < 4; ++t) {
                const float xv = s_x[rq + 4 * t][d];
                aq[t] = fmaf(xv, w0, aq[t]);
                ak[t] = fmaf(xv, w1, ak[t]);
                av[t] = fmaf(xv, w2, av[t]);
            }
        }
#pragma unroll
        for (int t = 0; t < 4; ++t) {
            const int row = r0 + rq + 4 * t;
            if (row < n) {
                qkvp[(size_t)row * QKVW + c]       = (uint16_t)f2bf_s(aq[t]);
                qkvp[(size_t)row * QKVW + 64 + c]  = (uint16_t)f2bf_s(ak[t]);
                qkvp[(size_t)row * QKVW + 128 + c] = (uint16_t)f2bf_s(av[t]);
            }
        }
    } else {
        int t = (blockIdx.x - nqkvb) * 256 + tid;
        if (t >= 36864) return;
        int j = t & 7, lane = (t >> 3) & 63, tile = t >> 9;
        int g = lane >> 4, nb = lane & 15;
        if (tile < 32) {
            int mt = tile >> 1, kt = tile & 1;
            w1p[t] = (uint16_t)f2bf_s(am_w1[(32 * kt + 8 * g + j) * 256 + 16 * mt + nb]);
        } else if (tile < 64) {
            int tt = tile - 32;
            int mt = tt >> 3, kt = tt & 7;
            w2p[t - 16384] = (uint16_t)f2bf_s(am_w2[(32 * kt + 8 * g + j) * 64 + 16 * mt + nb]);
        } else {
            int tt = tile - 64;
            int nt = tt >> 1, kt = tt & 1;
            pw2p[t - 32768] = (uint16_t)f2bf_s(pm_w2[(32 * kt + 8 * g + j) * 64 + 16 * nt + nb]);
        }
    }
}

// ---------------------------------------------------------------------------
// Main: round-13 structure (4 waves, 4 points/iter, 2 barriers per 4 points,
// dedup'd t-build) + two fixes:
//  (a) s_rel/s_vrel accessed via rv_off row-XOR swizzle: the b16
//      scatter-writes/reads drop from 8-way to <=2-way bank conflicts.
//  (b) biases absorbed into MFMA C-init: P1 racc = bias - q (broadcast),
//      P2 hacc = am_b1 float4 — deletes ~110 VALU adds/wave/group.
// Hazards unchanged: P3 reads s_h2/s_vrel only; next P1 writes s_rel/s_tf.
// ---------------------------------------------------------------------------
__global__ __launch_bounds__(256, 2) void ptl_main(
    const float* __restrict__ pos,
    const int* __restrict__ aidx,
    const uint8_t* __restrict__ mask,
    const float* __restrict__ pm_w1,
    const float* __restrict__ pm_b1,
    const float* __restrict__ pm_b2,
    const float* __restrict__ am_b1,
    const uint16_t* __restrict__ qkvp,
    const uint16_t* __restrict__ w1p,
    const uint16_t* __restrict__ w2p,
    const uint16_t* __restrict__ pw2p,
    float* __restrict__ out,
    int npts)
{
    const int tid  = threadIdx.x;
    const int w    = tid >> 6;
    const int lane = tid & 63;
    const int g    = lane >> 4;
    const int nb   = lane & 15;

    __shared__ alignas(16) uint16_t s_rel[64][80];      // rel' = rel + b2 - q (swz)
    __shared__ alignas(16) uint16_t s_vrel[64][80];     // v + rel (swz)
    __shared__ alignas(16) uint16_t s_h2[64][256];      // slot-XOR swizzled
    __shared__ alignas(16) uint16_t s_tf[4][64][16];    // t B-frags, own-slot

    char* relb  = (char*)&s_rel[0][0];
    char* vrelb = (char*)&s_vrel[0][0];

    // register-resident weights (64 VGPR)
    bf16x8 aw1[4][2], aw2[8];
#pragma unroll
    for (int m = 0; m < 4; ++m)
#pragma unroll
        for (int kt = 0; kt < 2; ++kt)
            aw1[m][kt] = *(const bf16x8*)(w1p + (size_t)(((4 * w + m) * 2 + kt) * 64 + lane) * 8);
#pragma unroll
    for (int kt = 0; kt < 8; ++kt)
        aw2[kt] = *(const bf16x8*)(w2p + (size_t)((w * 8 + kt) * 64 + lane) * 8);

    const int ngroups = (npts + 3) >> 2;

    // cross-iteration prefetch state (~15 VGPR)
    int   pnw;
    float cx, cy, cz, prx, pry, prz;
    bf16x8 pk0, pk1;

    auto stage_load = [&](int gbn) {
        const int gcl = min(gbn, ngroups - 1);
        const int ipn = min(gcl * 4 + w, npts - 1);
        pnw = aidx[ipn * KNB + nb];
        cx = pos[3 * ipn]; cy = pos[3 * ipn + 1]; cz = pos[3 * ipn + 2];
        prx = pos[3 * pnw]; pry = pos[3 * pnw + 1]; prz = pos[3 * pnw + 2];
        pk0 = *(const bf16x8*)(qkvp + (size_t)pnw * QKVW + 64 + 8 * g);
        pk1 = *(const bf16x8*)(qkvp + (size_t)pnw * QKVW + 96 + 8 * g);
    };

    stage_load(blockIdx.x);

    for (int gb = blockIdx.x; gb < ngroups; gb += gridDim.x) {
        const int i0  = gb * 4;
        const int ipw = min(i0 + w, npts - 1);

        // ================= P1: rel' + t-frags for point w ====================
        {
            // hoist q loads (consumed ~300cy later, after h1 build)
            uint16_t qv_u[4];
#pragma unroll
            for (int nt = 0; nt < 4; ++nt)
                qv_u[nt] = qkvp[(size_t)ipw * QKVW + 16 * nt + nb];

            const float rx = prx - cx, ry = pry - cy, rz = prz - cz;

            bf16x8 h1f[2];
#pragma unroll
            for (int kt = 0; kt < 2; ++kt) {
                const int hb = 32 * kt + 8 * g;
                float w0[8], w1r[8], w2r[8], bb[8];
                *(float4*)&w0[0]  = *(const float4*)(pm_w1 + hb);
                *(float4*)&w0[4]  = *(const float4*)(pm_w1 + hb + 4);
                *(float4*)&w1r[0] = *(const float4*)(pm_w1 + 64 + hb);
                *(float4*)&w1r[4] = *(const float4*)(pm_w1 + 64 + hb + 4);
                *(float4*)&w2r[0] = *(const float4*)(pm_w1 + 128 + hb);
                *(float4*)&w2r[4] = *(const float4*)(pm_w1 + 128 + hb + 4);
                *(float4*)&bb[0]  = *(const float4*)(pm_b1 + hb);
                *(float4*)&bb[4]  = *(const float4*)(pm_b1 + hb + 4);
                bf16x8 f;
#pragma unroll
                for (int jj = 0; jj < 8; ++jj) {
                    float v = fmaf(rx, w0[jj], fmaf(ry, w1r[jj], fmaf(rz, w2r[jj], bb[jj])));
                    f[jj] = f2bf_s(fmaxf(v, 0.f));
                }
                h1f[kt] = f;
            }
#pragma unroll
            for (int nt = 0; nt < 4; ++nt) {
                const int ch = 16 * nt + nb;
                const float bq = pm_b2[ch] - bf2f(qv_u[nt]);   // bias - q -> C-init
                const bf16x8 b0 = *(const bf16x8*)(pw2p + (size_t)((nt * 2 + 0) * 64 + lane) * 8);
                const bf16x8 b1 = *(const bf16x8*)(pw2p + (size_t)((nt * 2 + 1) * 64 + lane) * 8);
                f32x4 acc = {bq, bq, bq, bq};
                acc = __builtin_amdgcn_mfma_f32_16x16x32_bf16(h1f[0], b0, acc, 0, 0, 0);
                acc = __builtin_amdgcn_mfma_f32_16x16x32_bf16(h1f[1], b1, acc, 0, 0, 0);
#pragma unroll
                for (int r = 0; r < 4; ++r)
                    *(uint16_t*)(relb + rv_off(16 * w + 4 * g + r, 2 * ch)) =
                        (uint16_t)f2bf_s(acc[r]);
            }

            // wave-internal: t-frags for point w (k prefetched in registers)
            const bf16x8 rl0 = *(const bf16x8*)(relb + rv_off(16 * w + nb, 16 * g));
            const bf16x8 rl1 = *(const bf16x8*)(relb + rv_off(16 * w + nb, 64 + 16 * g));
            bf16x8 tf0, tf1;
#pragma unroll
            for (int j = 0; j < 8; ++j) {
                tf0[j] = f2bf_s(bf2f((uint16_t)pk0[j]) + bf2f((uint16_t)rl0[j]));
                tf1[j] = f2bf_s(bf2f((uint16_t)pk1[j]) + bf2f((uint16_t)rl1[j]));
            }
            *(bf16x8*)&s_tf[w][lane][0] = tf0;
            *(bf16x8*)&s_tf[w][lane][8] = tf1;
        }
        __syncthreads();   // barrier-1

        // ================= P2: h2 stripes (lean: ds_read + MFMA) =============
        {
            // early-issue owner loads for vrel (consumed after MFMA block)
            const bf16x8 pv0 = *(const bf16x8*)(qkvp + (size_t)pnw * QKVW + 128 + 8 * g);
            const bf16x8 pv1 = *(const bf16x8*)(qkvp + (size_t)pnw * QKVW + 160 + 8 * g);
            const bf16x8 pq0 = *(const bf16x8*)(qkvp + (size_t)ipw * QKVW + 8 * g);
            const bf16x8 pq1 = *(const bf16x8*)(qkvp + (size_t)ipw * QKVW + 32 + 8 * g);

#pragma unroll
            for (int pt = 0; pt < 4; ++pt) {
                const bf16x8 tf0 = *(const bf16x8*)&s_tf[pt][lane][0];
                const bf16x8 tf1 = *(const bf16x8*)&s_tf[pt][lane][8];

                f32x4 hacc[4];
                __builtin_amdgcn_s_setprio(1);
#pragma unroll
                for (int m = 0; m < 4; ++m) {
                    const float4 b4 = *(const float4*)(am_b1 + 16 * (4 * w + m) + 4 * g);
                    f32x4 a = {b4.x, b4.y, b4.z, b4.w};   // bias -> C-init
                    a = __builtin_amdgcn_mfma_f32_16x16x32_bf16(aw1[m][0], tf0, a, 0, 0, 0);
                    a = __builtin_amdgcn_mfma_f32_16x16x32_bf16(aw1[m][1], tf1, a, 0, 0, 0);
                    hacc[m] = a;
                }
                __builtin_amdgcn_s_setprio(0);
#pragma unroll
                for (int m = 0; m < 4; ++m) {
                    const uint32_t lo = (uint32_t)(uint16_t)f2bf_s(fmaxf(hacc[m][0], 0.f))
                                      | ((uint32_t)(uint16_t)f2bf_s(fmaxf(hacc[m][1], 0.f)) << 16);
                    const uint32_t hi = (uint32_t)(uint16_t)f2bf_s(fmaxf(hacc[m][2], 0.f))
                                      | ((uint32_t)(uint16_t)f2bf_s(fmaxf(hacc[m][3], 0.f)) << 16);
                    const int sl = (2 * (4 * w + m) + (g >> 1)) ^ (nb & 7);
                    *(uint2*)((char*)&s_h2[16 * pt + nb][0] + sl * 16 + 8 * (g & 1)) = make_uint2(lo, hi);
                }
            }

            // vrel = v + rel' + q for point w (pnw held — no aidx re-gather)
            {
                const bf16x8 rl0 = *(const bf16x8*)(relb + rv_off(16 * w + nb, 16 * g));
                const bf16x8 rl1 = *(const bf16x8*)(relb + rv_off(16 * w + nb, 64 + 16 * g));
                bf16x8 va, vb;
#pragma unroll
                for (int j = 0; j < 8; ++j) {
                    va[j] = f2bf_s(bf2f((uint16_t)pv0[j]) + bf2f((uint16_t)rl0[j]) + bf2f((uint16_t)pq0[j]));
                    vb[j] = f2bf_s(bf2f((uint16_t)pv1[j]) + bf2f((uint16_t)rl1[j]) + bf2f((uint16_t)pq1[j]));
                }
                *(bf16x8*)(vrelb + rv_off(16 * w + nb, 16 * g))      = va;
                *(bf16x8*)(vrelb + rv_off(16 * w + nb, 64 + 16 * g)) = vb;
            }
        }
        __syncthreads();   // barrier-2

        // ================= P3: stage next group, scores+softmax+agg ==========
        stage_load(gb + gridDim.x);

#pragma unroll
        for (int mt = 0; mt < 4; ++mt) {
            const int ip  = i0 + mt;
            const int ipc = min(ip, npts - 1);

            f32x4 wacc = {0.f, 0.f, 0.f, 0.f};
            __builtin_amdgcn_s_setprio(1);
#pragma unroll
            for (int kt = 0; kt < 8; ++kt) {
                const int sl = (4 * kt + g) ^ (nb & 7);
                const bf16x8 a = *(const bf16x8*)((const char*)&s_h2[16 * mt + nb][0] + sl * 16);
                wacc = __builtin_amdgcn_mfma_f32_16x16x32_bf16(a, aw2[kt], wacc, 0, 0, 0);
            }
            __builtin_amdgcn_s_setprio(0);

            const uchar4 m4 = *(const uchar4*)(mask + (size_t)ipc * KNB + 4 * g);
            const float sc0 = m4.x ? -INFINITY : wacc[0];
            const float sc1 = m4.y ? -INFINITY : wacc[1];
            const float sc2 = m4.z ? -INFINITY : wacc[2];
            const float sc3 = m4.w ? -INFINITY : wacc[3];
            float mx = fmaxf(fmaxf(sc0, sc1), fmaxf(sc2, sc3));
            mx = fmaxf(mx, __shfl_xor(mx, 16));
            mx = fmaxf(mx, __shfl_xor(mx, 32));
            const float e0 = __expf(sc0 - mx), e1 = __expf(sc1 - mx);
            const float e2 = __expf(sc2 - mx), e3 = __expf(sc3 - mx);
            float den = (e0 + e1) + (e2 + e3);

            const int vcb = 2 * (16 * w + nb);
            const float vr0 = bf2f(*(const uint16_t*)(vrelb + rv_off(16 * mt + 4 * g + 0, vcb)));
            const float vr1 = bf2f(*(const uint16_t*)(vrelb + rv_off(16 * mt + 4 * g + 1, vcb)));
            const float vr2 = bf2f(*(const uint16_t*)(vrelb + rv_off(16 * mt + 4 * g + 2, vcb)));
            const float vr3 = bf2f(*(const uint16_t*)(vrelb + rv_off(16 * mt + 4 * g + 3, vcb)));
            float num = e0 * vr0;
            num = fmaf(e1, vr1, num);
            num = fmaf(e2, vr2, num);
            num = fmaf(e3, vr3, num);

            den += __shfl_xor(den, 16); den += __shfl_xor(den, 32);
            num += __shfl_xor(num, 16); num += __shfl_xor(num, 32);
            if (lane < 16 && ip < npts)
                out[(size_t)ip * 64 + 16 * w + nb] = __fdividef(num, den);
        }
        // no third barrier needed (see header comment)
    }
}

// ---------------------------------------------------------------------------
extern "C" void kernel_launch(void* const* d_in, const int* in_sizes, int n_in,
                              void* d_out, int out_size, void* d_ws, size_t ws_size,
                              hipStream_t stream) {
    const float*   x     = (const float*)d_in[0];
    const float*   pos   = (const float*)d_in[1];
    const int*     aidx  = (const int*)d_in[2];
    const uint8_t* mask  = (const uint8_t*)d_in[3];
    const float*   wqkv  = (const float*)d_in[4];
    const float*   pm_w1 = (const float*)d_in[5];
    const float*   pm_b1 = (const float*)d_in[6];
    const float*   pm_w2 = (const float*)d_in[7];
    const float*   pm_b2 = (const float*)d_in[8];
    const float*   am_w1 = (const float*)d_in[9];
    const float*   am_b1 = (const float*)d_in[10];
    const float*   am_w2 = (const float*)d_in[11];
    // am_b2 (d_in[12]) is constant over the softmax axis -> cancels, unused
    float* out = (float*)d_out;
    const int n = in_sizes[0] / DIM;

    uint8_t* ws = (uint8_t*)d_ws;
    uint16_t* qkvp = (uint16_t*)ws;                               // n*192 bf16
    uint16_t* w1p  = (uint16_t*)(ws + (size_t)n * QKVW * 2);      // 16384 bf16
    uint16_t* w2p  = w1p + 16384;                                 // 16384 bf16
    uint16_t* pw2p = w2p + 16384;                                 // 4096 bf16

    const int nqkvb = (n + 15) / 16;
    prep_kernel<<<nqkvb + 144, 256, 0, stream>>>(x, wqkv, am_w1, am_w2, pm_w2,
                                                 qkvp, w1p, w2p, pw2p, n, nqkvb);
    ptl_main<<<512, 256, 0, stream>>>(pos, aidx, mask, pm_w1, pm_b1, pm_b2, am_b1,
                                      qkvp, w1p, w2p, pw2p, out, n);
}

// Round 15
// 171.594 us; speedup vs baseline: 1.1482x; 1.1482x over previous
//
#include <hip/hip_runtime.h>
#include <hip/hip_bf16.h>
#include <math.h>
#include <stdint.h>

#define DIM   64
#define KNB   16
#define QKVW  192
#define RVP   72    // rel/vrel row = 144B: row-base bank walks 4/row -> scatters 2-way
#define TFP   24    // s_tf row = 48B: spreads the 32B-stride 4-bank pileup

typedef short bf16x8 __attribute__((ext_vector_type(8)));
typedef float f32x4  __attribute__((ext_vector_type(4)));

__device__ __forceinline__ short f2bf_s(float x) {
    return (short)__builtin_bit_cast(unsigned short, __float2bfloat16(x));
}
__device__ __forceinline__ float bf2f(uint16_t u) {
    uint32_t v = ((uint32_t)u) << 16;
    return __builtin_bit_cast(float, v);
}

// ---------------------------------------------------------------------------
// prep: qkv projection (blocks < nqkvb) + weight prepack (remaining blocks).
// qkv -> bf16 [N][192] (q|k|v). Fragment: non-K = lane&15, K = 32kt+8(lane>>4)+j.
// ---------------------------------------------------------------------------
__global__ __launch_bounds__(256) void prep_kernel(
    const float* __restrict__ x, const float* __restrict__ wqkv,
    const float* __restrict__ am_w1, const float* __restrict__ am_w2,
    const float* __restrict__ pm_w2,
    uint16_t* __restrict__ qkvp, uint16_t* __restrict__ w1p,
    uint16_t* __restrict__ w2p, uint16_t* __restrict__ pw2p,
    int n, int nqkvb)
{
    const int tid = threadIdx.x;
    if (blockIdx.x < nqkvb) {
        const int c  = tid & 63;
        const int rq = tid >> 6;
        const int r0 = blockIdx.x * 16;
        __shared__ float s_x[16][64];
#pragma unroll
        for (int t = 0; t < 4; ++t) {
            const int row = r0 + rq + 4 * t;
            s_x[rq + 4 * t][c] = (row < n) ? x[(size_t)row * 64 + c] : 0.f;
        }
        __syncthreads();
        float aq[4] = {0, 0, 0, 0}, ak[4] = {0, 0, 0, 0}, av[4] = {0, 0, 0, 0};
        for (int d = 0; d < 64; ++d) {
            const float w0 = wqkv[d * QKVW + c];
            const float w1 = wqkv[d * QKVW + 64 + c];
            const float w2 = wqkv[d * QKVW + 128 + c];
#pragma unroll
            for (int t = 0; t < 4; ++t) {
                const float xv = s_x[rq + 4 * t][d];
                aq[t] = fmaf(xv, w0, aq[t]);
                ak[t] = fmaf(xv, w1, ak[t]);
                av[t] = fmaf(xv, w2, av[t]);
            }
        }
#pragma unroll
        for (int t = 0; t < 4; ++t) {
            const int row = r0 + rq + 4 * t;
            if (row < n) {
                qkvp[(size_t)row * QKVW + c]       = (uint16_t)f2bf_s(aq[t]);
                qkvp[(size_t)row * QKVW + 64 + c]  = (uint16_t)f2bf_s(ak[t]);
                qkvp[(size_t)row * QKVW + 128 + c] = (uint16_t)f2bf_s(av[t]);
            }
        }
    } else {
        int t = (blockIdx.x - nqkvb) * 256 + tid;
        if (t >= 36864) return;
        int j = t & 7, lane = (t >> 3) & 63, tile = t >> 9;
        int g = lane >> 4, nb = lane & 15;
        if (tile < 32) {
            int mt = tile >> 1, kt = tile & 1;
            w1p[t] = (uint16_t)f2bf_s(am_w1[(32 * kt + 8 * g + j) * 256 + 16 * mt + nb]);
        } else if (tile < 64) {
            int tt = tile - 32;
            int mt = tt >> 3, kt = tt & 7;
            w2p[t - 16384] = (uint16_t)f2bf_s(am_w2[(32 * kt + 8 * g + j) * 64 + 16 * mt + nb]);
        } else {
            int tt = tile - 64;
            int nt = tt >> 1, kt = tt & 1;
            pw2p[t - 32768] = (uint16_t)f2bf_s(pm_w2[(32 * kt + 8 * g + j) * 64 + 16 * nt + nb]);
        }
    }
}

// ---------------------------------------------------------------------------
// Main: round-13 structure verbatim (4 waves, 4 points/iter, 2 barriers per
// 4 points, dedup'd t-build, register k-prefetch) with bank-conflict fixes
// done purely via compile-time row strides (VGPR-neutral — r14's runtime-XOR
// + C-init variant spilled at the 128-VGPR cap):
//   s_rel/s_vrel rows 160B -> 144B: b16 scatters drop 8-way -> 2-way (free).
//   s_tf rows 32B -> 48B: own-slot b128 ops spread off the 4-bank pileup.
// Hazards: P3 reads s_h2/s_vrel only; next P1 writes s_rel/s_tf (unread by
// P3); P2' writes (s_h2/s_vrel) are behind barrier-1'.
// ---------------------------------------------------------------------------
__global__ __launch_bounds__(256, 2) void ptl_main(
    const float* __restrict__ pos,
    const int* __restrict__ aidx,
    const uint8_t* __restrict__ mask,
    const float* __restrict__ pm_w1,
    const float* __restrict__ pm_b1,
    const float* __restrict__ pm_b2,
    const float* __restrict__ am_b1,
    const uint16_t* __restrict__ qkvp,
    const uint16_t* __restrict__ w1p,
    const uint16_t* __restrict__ w2p,
    const uint16_t* __restrict__ pw2p,
    float* __restrict__ out,
    int npts)
{
    const int tid  = threadIdx.x;
    const int w    = tid >> 6;
    const int lane = tid & 63;
    const int g    = lane >> 4;
    const int nb   = lane & 15;

    __shared__ alignas(16) uint16_t s_rel[4][16][RVP];  // rel' = rel + b2 - q
    __shared__ alignas(16) uint16_t s_vrel[64][RVP];    // v + rel
    __shared__ alignas(16) uint16_t s_h2[64][256];      // slot-XOR swizzled
    __shared__ alignas(16) uint16_t s_tf[4][64][TFP];   // t B-frags, own-slot

    // register-resident weights (64 VGPR)
    bf16x8 aw1[4][2], aw2[8];
#pragma unroll
    for (int m = 0; m < 4; ++m)
#pragma unroll
        for (int kt = 0; kt < 2; ++kt)
            aw1[m][kt] = *(const bf16x8*)(w1p + (size_t)(((4 * w + m) * 2 + kt) * 64 + lane) * 8);
#pragma unroll
    for (int kt = 0; kt < 8; ++kt)
        aw2[kt] = *(const bf16x8*)(w2p + (size_t)((w * 8 + kt) * 64 + lane) * 8);

    const int ngroups = (npts + 3) >> 2;

    // cross-iteration prefetch state (~15 VGPR)
    int   pnw;
    float cx, cy, cz, prx, pry, prz;
    bf16x8 pk0, pk1;

    auto stage_load = [&](int gbn) {
        const int gcl = min(gbn, ngroups - 1);
        const int ipn = min(gcl * 4 + w, npts - 1);
        pnw = aidx[ipn * KNB + nb];
        cx = pos[3 * ipn]; cy = pos[3 * ipn + 1]; cz = pos[3 * ipn + 2];
        prx = pos[3 * pnw]; pry = pos[3 * pnw + 1]; prz = pos[3 * pnw + 2];
        pk0 = *(const bf16x8*)(qkvp + (size_t)pnw * QKVW + 64 + 8 * g);
        pk1 = *(const bf16x8*)(qkvp + (size_t)pnw * QKVW + 96 + 8 * g);
    };

    stage_load(blockIdx.x);

    for (int gb = blockIdx.x; gb < ngroups; gb += gridDim.x) {
        const int i0  = gb * 4;
        const int ipw = min(i0 + w, npts - 1);

        // ================= P1: rel' + t-frags for point w ====================
        {
            const float rx = prx - cx, ry = pry - cy, rz = prz - cz;

            bf16x8 h1f[2];
#pragma unroll
            for (int kt = 0; kt < 2; ++kt) {
                const int hb = 32 * kt + 8 * g;
                float w0[8], w1r[8], w2r[8], bb[8];
                *(float4*)&w0[0]  = *(const float4*)(pm_w1 + hb);
                *(float4*)&w0[4]  = *(const float4*)(pm_w1 + hb + 4);
                *(float4*)&w1r[0] = *(const float4*)(pm_w1 + 64 + hb);
                *(float4*)&w1r[4] = *(const float4*)(pm_w1 + 64 + hb + 4);
                *(float4*)&w2r[0] = *(const float4*)(pm_w1 + 128 + hb);
                *(float4*)&w2r[4] = *(const float4*)(pm_w1 + 128 + hb + 4);
                *(float4*)&bb[0]  = *(const float4*)(pm_b1 + hb);
                *(float4*)&bb[4]  = *(const float4*)(pm_b1 + hb + 4);
                bf16x8 f;
#pragma unroll
                for (int jj = 0; jj < 8; ++jj) {
                    float v = fmaf(rx, w0[jj], fmaf(ry, w1r[jj], fmaf(rz, w2r[jj], bb[jj])));
                    f[jj] = f2bf_s(fmaxf(v, 0.f));
                }
                h1f[kt] = f;
            }
#pragma unroll
            for (int nt = 0; nt < 4; ++nt) {
                const bf16x8 b0 = *(const bf16x8*)(pw2p + (size_t)((nt * 2 + 0) * 64 + lane) * 8);
                const bf16x8 b1 = *(const bf16x8*)(pw2p + (size_t)((nt * 2 + 1) * 64 + lane) * 8);
                f32x4 acc = {0.f, 0.f, 0.f, 0.f};
                acc = __builtin_amdgcn_mfma_f32_16x16x32_bf16(h1f[0], b0, acc, 0, 0, 0);
                acc = __builtin_amdgcn_mfma_f32_16x16x32_bf16(h1f[1], b1, acc, 0, 0, 0);
                const int ch = 16 * nt + nb;
                const float bias = pm_b2[ch];
                const float qv = bf2f(qkvp[(size_t)ipw * QKVW + ch]);  // fold -q
#pragma unroll
                for (int r = 0; r < 4; ++r)
                    s_rel[w][4 * g + r][ch] = (uint16_t)f2bf_s(acc[r] + bias - qv);
            }

            // wave-internal: t-frags for point w (k prefetched in registers).
            const bf16x8 rl0 = *(const bf16x8*)&s_rel[w][nb][8 * g];
            const bf16x8 rl1 = *(const bf16x8*)&s_rel[w][nb][32 + 8 * g];
            bf16x8 tf0, tf1;
#pragma unroll
            for (int j = 0; j < 8; ++j) {
                tf0[j] = f2bf_s(bf2f((uint16_t)pk0[j]) + bf2f((uint16_t)rl0[j]));
                tf1[j] = f2bf_s(bf2f((uint16_t)pk1[j]) + bf2f((uint16_t)rl1[j]));
            }
            *(bf16x8*)&s_tf[w][lane][0] = tf0;
            *(bf16x8*)&s_tf[w][lane][8] = tf1;
        }
        __syncthreads();   // barrier-1

        // ================= P2: h2 stripes (lean: ds_read + MFMA) =============
        {
            // early-issue owner loads for vrel (consumed after MFMA block)
            const bf16x8 pv0 = *(const bf16x8*)(qkvp + (size_t)pnw * QKVW + 128 + 8 * g);
            const bf16x8 pv1 = *(const bf16x8*)(qkvp + (size_t)pnw * QKVW + 160 + 8 * g);
            const bf16x8 pq0 = *(const bf16x8*)(qkvp + (size_t)ipw * QKVW + 8 * g);
            const bf16x8 pq1 = *(const bf16x8*)(qkvp + (size_t)ipw * QKVW + 32 + 8 * g);

#pragma unroll
            for (int pt = 0; pt < 4; ++pt) {
                const bf16x8 tf0 = *(const bf16x8*)&s_tf[pt][lane][0];
                const bf16x8 tf1 = *(const bf16x8*)&s_tf[pt][lane][8];

                f32x4 hacc[4];
                __builtin_amdgcn_s_setprio(1);
#pragma unroll
                for (int m = 0; m < 4; ++m) {
                    f32x4 a = {0.f, 0.f, 0.f, 0.f};
                    a = __builtin_amdgcn_mfma_f32_16x16x32_bf16(aw1[m][0], tf0, a, 0, 0, 0);
                    a = __builtin_amdgcn_mfma_f32_16x16x32_bf16(aw1[m][1], tf1, a, 0, 0, 0);
                    hacc[m] = a;
                }
                __builtin_amdgcn_s_setprio(0);
#pragma unroll
                for (int m = 0; m < 4; ++m) {
                    const int hb = 16 * (4 * w + m) + 4 * g;
                    const float4 b4 = *(const float4*)(am_b1 + hb);
                    const uint32_t lo = (uint32_t)(uint16_t)f2bf_s(fmaxf(hacc[m][0] + b4.x, 0.f))
                                      | ((uint32_t)(uint16_t)f2bf_s(fmaxf(hacc[m][1] + b4.y, 0.f)) << 16);
                    const uint32_t hi = (uint32_t)(uint16_t)f2bf_s(fmaxf(hacc[m][2] + b4.z, 0.f))
                                      | ((uint32_t)(uint16_t)f2bf_s(fmaxf(hacc[m][3] + b4.w, 0.f)) << 16);
                    const int sl = (2 * (4 * w + m) + (g >> 1)) ^ (nb & 7);
                    *(uint2*)((char*)&s_h2[16 * pt + nb][0] + sl * 16 + 8 * (g & 1)) = make_uint2(lo, hi);
                }
            }

            // vrel = v + rel' + q for point w (pnw held — no aidx re-gather)
            {
                const bf16x8 rl0 = *(const bf16x8*)&s_rel[w][nb][8 * g];
                const bf16x8 rl1 = *(const bf16x8*)&s_rel[w][nb][32 + 8 * g];
                bf16x8 va, vb;
#pragma unroll
                for (int j = 0; j < 8; ++j) {
                    va[j] = f2bf_s(bf2f((uint16_t)pv0[j]) + bf2f((uint16_t)rl0[j]) + bf2f((uint16_t)pq0[j]));
                    vb[j] = f2bf_s(bf2f((uint16_t)pv1[j]) + bf2f((uint16_t)rl1[j]) + bf2f((uint16_t)pq1[j]));
                }
                *(bf16x8*)&s_vrel[16 * w + nb][8 * g]      = va;
                *(bf16x8*)&s_vrel[16 * w + nb][32 + 8 * g] = vb;
            }
        }
        __syncthreads();   // barrier-2

        // ================= P3: stage next group, scores+softmax+agg ==========
        stage_load(gb + gridDim.x);

#pragma unroll
        for (int mt = 0; mt < 4; ++mt) {
            const int ip  = i0 + mt;
            const int ipc = min(ip, npts - 1);

            f32x4 wacc = {0.f, 0.f, 0.f, 0.f};
            __builtin_amdgcn_s_setprio(1);
#pragma unroll
            for (int kt = 0; kt < 8; ++kt) {
                const int sl = (4 * kt + g) ^ (nb & 7);
                const bf16x8 a = *(const bf16x8*)((const char*)&s_h2[16 * mt + nb][0] + sl * 16);
                wacc = __builtin_amdgcn_mfma_f32_16x16x32_bf16(a, aw2[kt], wacc, 0, 0, 0);
            }
            __builtin_amdgcn_s_setprio(0);

            const uchar4 m4 = *(const uchar4*)(mask + (size_t)ipc * KNB + 4 * g);
            const float sc0 = m4.x ? -INFINITY : wacc[0];
            const float sc1 = m4.y ? -INFINITY : wacc[1];
            const float sc2 = m4.z ? -INFINITY : wacc[2];
            const float sc3 = m4.w ? -INFINITY : wacc[3];
            float mx = fmaxf(fmaxf(sc0, sc1), fmaxf(sc2, sc3));
            mx = fmaxf(mx, __shfl_xor(mx, 16));
            mx = fmaxf(mx, __shfl_xor(mx, 32));
            const float e0 = __expf(sc0 - mx), e1 = __expf(sc1 - mx);
            const float e2 = __expf(sc2 - mx), e3 = __expf(sc3 - mx);
            float den = (e0 + e1) + (e2 + e3);

            const int vc = 16 * w + nb;
            const float vr0 = bf2f(s_vrel[16 * mt + 4 * g + 0][vc]);
            const float vr1 = bf2f(s_vrel[16 * mt + 4 * g + 1][vc]);
            const float vr2 = bf2f(s_vrel[16 * mt + 4 * g + 2][vc]);
            const float vr3 = bf2f(s_vrel[16 * mt + 4 * g + 3][vc]);
            float num = e0 * vr0;
            num = fmaf(e1, vr1, num);
            num = fmaf(e2, vr2, num);
            num = fmaf(e3, vr3, num);

            den += __shfl_xor(den, 16); den += __shfl_xor(den, 32);
            num += __shfl_xor(num, 16); num += __shfl_xor(num, 32);
            if (lane < 16 && ip < npts)
                out[(size_t)ip * 64 + vc] = __fdividef(num, den);
        }
        // no third barrier needed (see header comment)
    }
}

// ---------------------------------------------------------------------------
extern "C" void kernel_launch(void* const* d_in, const int* in_sizes, int n_in,
                              void* d_out, int out_size, void* d_ws, size_t ws_size,
                              hipStream_t stream) {
    const float*   x     = (const float*)d_in[0];
    const float*   pos   = (const float*)d_in[1];
    const int*     aidx  = (const int*)d_in[2];
    const uint8_t* mask  = (const uint8_t*)d_in[3];
    const float*   wqkv  = (const float*)d_in[4];
    const float*   pm_w1 = (const float*)d_in[5];
    const float*   pm_b1 = (const float*)d_in[6];
    const float*   pm_w2 = (const float*)d_in[7];
    const float*   pm_b2 = (const float*)d_in[8];
    const float*   am_w1 = (const float*)d_in[9];
    const float*   am_b1 = (const float*)d_in[10];
    const float*   am_w2 = (const float*)d_in[11];
    // am_b2 (d_in[12]) is constant over the softmax axis -> cancels, unused
    float* out = (float*)d_out;
    const int n = in_sizes[0] / DIM;

    uint8_t* ws = (uint8_t*)d_ws;
    uint16_t* qkvp = (uint16_t*)ws;                               // n*192 bf16
    uint16_t* w1p  = (uint16_t*)(ws + (size_t)n * QKVW * 2);      // 16384 bf16
    uint16_t* w2p  = w1p + 16384;                                 // 16384 bf16
    uint16_t* pw2p = w2p + 16384;                                 // 4096 bf16

    const int nqkvb = (n + 15) / 16;
    prep_kernel<<<nqkvb + 144, 256, 0, stream>>>(x, wqkv, am_w1, am_w2, pm_w2,
                                                 qkvp, w1p, w2p, pw2p, n, nqkvb);
    ptl_main<<<512, 256, 0, stream>>>(pos, aidx, mask, pm_w1, pm_b1, pm_b2, am_b1,
                                      qkvp, w1p, w2p, pw2p, out, n);
}

// Round 16
// 159.886 us; speedup vs baseline: 1.2323x; 1.0732x over previous
//
#include <hip/hip_runtime.h>
#include <hip/hip_bf16.h>
#include <math.h>
#include <stdint.h>

#define DIM   64
#define KNB   16
#define QKVW  192
#define RVP   72    // rel/vrel row = 144B: row-base bank walks 4/row -> scatters 2-way
#define TFP   24    // s_tf row = 48B: spreads the 32B-stride 4-bank pileup

typedef short bf16x8 __attribute__((ext_vector_type(8)));
typedef float f32x4  __attribute__((ext_vector_type(4)));

__device__ __forceinline__ short f2bf_s(float x) {
    return (short)__builtin_bit_cast(unsigned short, __float2bfloat16(x));
}
__device__ __forceinline__ float bf2f(uint16_t u) {
    uint32_t v = ((uint32_t)u) << 16;
    return __builtin_bit_cast(float, v);
}

// ---------------------------------------------------------------------------
// prep: qkv projection via MFMA (blocks < nqkvb) + weight prepack (rest).
// qkv -> bf16 [N][192] (q|k|v). Fragment: non-K = lane&15, K = 32kt+8(lane>>4)+j.
// qkv-MFMA: 16 rows/block; wave w owns 3 of the 12 col-tiles; B-frags of
// wqkv built inline per wave (48 scalar f32 loads, L2-resident).
// Pattern identical to r10's verified xw_kernel (D: col=lane&15, row=4g+r).
// ---------------------------------------------------------------------------
__global__ __launch_bounds__(256) void prep_kernel(
    const float* __restrict__ x, const float* __restrict__ wqkv,
    const float* __restrict__ am_w1, const float* __restrict__ am_w2,
    const float* __restrict__ pm_w2,
    uint16_t* __restrict__ qkvp, uint16_t* __restrict__ w1p,
    uint16_t* __restrict__ w2p, uint16_t* __restrict__ pw2p,
    int n, int nqkvb)
{
    const int tid = threadIdx.x;
    if (blockIdx.x < nqkvb) {
        const int w4   = tid >> 6;
        const int lane = tid & 63;
        const int g    = lane >> 4;
        const int nb   = lane & 15;
        const int r0   = blockIdx.x * 16;
        const int rowA = min(r0 + nb, n - 1);

        // A-frags: x[rowA][32kt + 8g + j], f32 -> bf16
        bf16x8 af[2];
#pragma unroll
        for (int kt = 0; kt < 2; ++kt) {
            const float* xr = x + (size_t)rowA * 64 + 32 * kt + 8 * g;
            const float4 a0 = *(const float4*)xr;
            const float4 a1 = *(const float4*)(xr + 4);
            bf16x8 f;
            f[0] = f2bf_s(a0.x); f[1] = f2bf_s(a0.y); f[2] = f2bf_s(a0.z); f[3] = f2bf_s(a0.w);
            f[4] = f2bf_s(a1.x); f[5] = f2bf_s(a1.y); f[6] = f2bf_s(a1.z); f[7] = f2bf_s(a1.w);
            af[kt] = f;
        }

#pragma unroll
        for (int t = 0; t < 3; ++t) {
            const int nt  = 3 * w4 + t;
            const int col = 16 * nt + nb;
            bf16x8 b0, b1;
#pragma unroll
            for (int j = 0; j < 8; ++j) {
                b0[j] = f2bf_s(wqkv[(8 * g + j) * QKVW + col]);
                b1[j] = f2bf_s(wqkv[(32 + 8 * g + j) * QKVW + col]);
            }
            f32x4 acc = {0.f, 0.f, 0.f, 0.f};
            acc = __builtin_amdgcn_mfma_f32_16x16x32_bf16(af[0], b0, acc, 0, 0, 0);
            acc = __builtin_amdgcn_mfma_f32_16x16x32_bf16(af[1], b1, acc, 0, 0, 0);
#pragma unroll
            for (int r = 0; r < 4; ++r) {
                const int row = r0 + 4 * g + r;
                if (row < n)
                    qkvp[(size_t)row * QKVW + col] = (uint16_t)f2bf_s(acc[r]);
            }
        }
    } else {
        int t = (blockIdx.x - nqkvb) * 256 + tid;
        if (t >= 36864) return;
        int j = t & 7, lane = (t >> 3) & 63, tile = t >> 9;
        int g = lane >> 4, nb = lane & 15;
        if (tile < 32) {
            int mt = tile >> 1, kt = tile & 1;
            w1p[t] = (uint16_t)f2bf_s(am_w1[(32 * kt + 8 * g + j) * 256 + 16 * mt + nb]);
        } else if (tile < 64) {
            int tt = tile - 32;
            int mt = tt >> 3, kt = tt & 7;
            w2p[t - 16384] = (uint16_t)f2bf_s(am_w2[(32 * kt + 8 * g + j) * 64 + 16 * mt + nb]);
        } else {
            int tt = tile - 64;
            int nt = tt >> 1, kt = tt & 1;
            pw2p[t - 32768] = (uint16_t)f2bf_s(pm_w2[(32 * kt + 8 * g + j) * 64 + 16 * nt + nb]);
        }
    }
}

// ---------------------------------------------------------------------------
// Main: round-15 structure (4 waves, 4 points/iter, 2 barriers per 4 points,
// dedup'd t-build, register k-prefetch, padded-stride LDS) with P1 made
// global-load-free: the q-fold gathers (qv) move into stage_load (previous
// iteration's P3), +2 VGPR. All other code identical to r15.
// Hazards: P3 reads s_h2/s_vrel only; next P1 writes s_rel/s_tf (unread by
// P3); P2' writes (s_h2/s_vrel) are behind barrier-1'.
// ---------------------------------------------------------------------------
__global__ __launch_bounds__(256, 2) void ptl_main(
    const float* __restrict__ pos,
    const int* __restrict__ aidx,
    const uint8_t* __restrict__ mask,
    const float* __restrict__ pm_w1,
    const float* __restrict__ pm_b1,
    const float* __restrict__ pm_b2,
    const float* __restrict__ am_b1,
    const uint16_t* __restrict__ qkvp,
    const uint16_t* __restrict__ w1p,
    const uint16_t* __restrict__ w2p,
    const uint16_t* __restrict__ pw2p,
    float* __restrict__ out,
    int npts)
{
    const int tid  = threadIdx.x;
    const int w    = tid >> 6;
    const int lane = tid & 63;
    const int g    = lane >> 4;
    const int nb   = lane & 15;

    __shared__ alignas(16) uint16_t s_rel[4][16][RVP];  // rel' = rel + b2 - q
    __shared__ alignas(16) uint16_t s_vrel[64][RVP];    // v + rel
    __shared__ alignas(16) uint16_t s_h2[64][256];      // slot-XOR swizzled
    __shared__ alignas(16) uint16_t s_tf[4][64][TFP];   // t B-frags, own-slot

    // register-resident weights (64 VGPR)
    bf16x8 aw1[4][2], aw2[8];
#pragma unroll
    for (int m = 0; m < 4; ++m)
#pragma unroll
        for (int kt = 0; kt < 2; ++kt)
            aw1[m][kt] = *(const bf16x8*)(w1p + (size_t)(((4 * w + m) * 2 + kt) * 64 + lane) * 8);
#pragma unroll
    for (int kt = 0; kt < 8; ++kt)
        aw2[kt] = *(const bf16x8*)(w2p + (size_t)((w * 8 + kt) * 64 + lane) * 8);

    const int ngroups = (npts + 3) >> 2;

    // cross-iteration prefetch state (~17 VGPR)
    int   pnw;
    float cx, cy, cz, prx, pry, prz;
    bf16x8 pk0, pk1;
    uint16_t pqv[4];   // q[ipw][16nt+nb] (statically indexed -> registers)

    auto stage_load = [&](int gbn) {
        const int gcl = min(gbn, ngroups - 1);
        const int ipn = min(gcl * 4 + w, npts - 1);
        pnw = aidx[ipn * KNB + nb];
        cx = pos[3 * ipn]; cy = pos[3 * ipn + 1]; cz = pos[3 * ipn + 2];
        prx = pos[3 * pnw]; pry = pos[3 * pnw + 1]; prz = pos[3 * pnw + 2];
        pk0 = *(const bf16x8*)(qkvp + (size_t)pnw * QKVW + 64 + 8 * g);
        pk1 = *(const bf16x8*)(qkvp + (size_t)pnw * QKVW + 96 + 8 * g);
#pragma unroll
        for (int nt = 0; nt < 4; ++nt)
            pqv[nt] = qkvp[(size_t)ipn * QKVW + 16 * nt + nb];
    };

    stage_load(blockIdx.x);

    for (int gb = blockIdx.x; gb < ngroups; gb += gridDim.x) {
        const int i0  = gb * 4;
        const int ipw = min(i0 + w, npts - 1);

        // ================= P1: rel' + t-frags for point w (no global loads) ==
        {
            const float rx = prx - cx, ry = pry - cy, rz = prz - cz;

            bf16x8 h1f[2];
#pragma unroll
            for (int kt = 0; kt < 2; ++kt) {
                const int hb = 32 * kt + 8 * g;
                float w0[8], w1r[8], w2r[8], bb[8];
                *(float4*)&w0[0]  = *(const float4*)(pm_w1 + hb);
                *(float4*)&w0[4]  = *(const float4*)(pm_w1 + hb + 4);
                *(float4*)&w1r[0] = *(const float4*)(pm_w1 + 64 + hb);
                *(float4*)&w1r[4] = *(const float4*)(pm_w1 + 64 + hb + 4);
                *(float4*)&w2r[0] = *(const float4*)(pm_w1 + 128 + hb);
                *(float4*)&w2r[4] = *(const float4*)(pm_w1 + 128 + hb + 4);
                *(float4*)&bb[0]  = *(const float4*)(pm_b1 + hb);
                *(float4*)&bb[4]  = *(const float4*)(pm_b1 + hb + 4);
                bf16x8 f;
#pragma unroll
                for (int jj = 0; jj < 8; ++jj) {
                    float v = fmaf(rx, w0[jj], fmaf(ry, w1r[jj], fmaf(rz, w2r[jj], bb[jj])));
                    f[jj] = f2bf_s(fmaxf(v, 0.f));
                }
                h1f[kt] = f;
            }
#pragma unroll
            for (int nt = 0; nt < 4; ++nt) {
                const bf16x8 b0 = *(const bf16x8*)(pw2p + (size_t)((nt * 2 + 0) * 64 + lane) * 8);
                const bf16x8 b1 = *(const bf16x8*)(pw2p + (size_t)((nt * 2 + 1) * 64 + lane) * 8);
                f32x4 acc = {0.f, 0.f, 0.f, 0.f};
                acc = __builtin_amdgcn_mfma_f32_16x16x32_bf16(h1f[0], b0, acc, 0, 0, 0);
                acc = __builtin_amdgcn_mfma_f32_16x16x32_bf16(h1f[1], b1, acc, 0, 0, 0);
                const int ch = 16 * nt + nb;
                const float bias = pm_b2[ch];
                const float qv = bf2f(pqv[nt]);          // prefetched in P3
#pragma unroll
                for (int r = 0; r < 4; ++r)
                    s_rel[w][4 * g + r][ch] = (uint16_t)f2bf_s(acc[r] + bias - qv);
            }

            // wave-internal: t-frags for point w (k prefetched in registers).
            const bf16x8 rl0 = *(const bf16x8*)&s_rel[w][nb][8 * g];
            const bf16x8 rl1 = *(const bf16x8*)&s_rel[w][nb][32 + 8 * g];
            bf16x8 tf0, tf1;
#pragma unroll
            for (int j = 0; j < 8; ++j) {
                tf0[j] = f2bf_s(bf2f((uint16_t)pk0[j]) + bf2f((uint16_t)rl0[j]));
                tf1[j] = f2bf_s(bf2f((uint16_t)pk1[j]) + bf2f((uint16_t)rl1[j]));
            }
            *(bf16x8*)&s_tf[w][lane][0] = tf0;
            *(bf16x8*)&s_tf[w][lane][8] = tf1;
        }
        __syncthreads();   // barrier-1

        // ================= P2: h2 stripes (lean: ds_read + MFMA) =============
        {
            // early-issue owner loads for vrel (consumed after MFMA block)
            const bf16x8 pv0 = *(const bf16x8*)(qkvp + (size_t)pnw * QKVW + 128 + 8 * g);
            const bf16x8 pv1 = *(const bf16x8*)(qkvp + (size_t)pnw * QKVW + 160 + 8 * g);
            const bf16x8 pq0 = *(const bf16x8*)(qkvp + (size_t)ipw * QKVW + 8 * g);
            const bf16x8 pq1 = *(const bf16x8*)(qkvp + (size_t)ipw * QKVW + 32 + 8 * g);

#pragma unroll
            for (int pt = 0; pt < 4; ++pt) {
                const bf16x8 tf0 = *(const bf16x8*)&s_tf[pt][lane][0];
                const bf16x8 tf1 = *(const bf16x8*)&s_tf[pt][lane][8];

                f32x4 hacc[4];
                __builtin_amdgcn_s_setprio(1);
#pragma unroll
                for (int m = 0; m < 4; ++m) {
                    f32x4 a = {0.f, 0.f, 0.f, 0.f};
                    a = __builtin_amdgcn_mfma_f32_16x16x32_bf16(aw1[m][0], tf0, a, 0, 0, 0);
                    a = __builtin_amdgcn_mfma_f32_16x16x32_bf16(aw1[m][1], tf1, a, 0, 0, 0);
                    hacc[m] = a;
                }
                __builtin_amdgcn_s_setprio(0);
#pragma unroll
                for (int m = 0; m < 4; ++m) {
                    const int hb = 16 * (4 * w + m) + 4 * g;
                    const float4 b4 = *(const float4*)(am_b1 + hb);
                    const uint32_t lo = (uint32_t)(uint16_t)f2bf_s(fmaxf(hacc[m][0] + b4.x, 0.f))
                                      | ((uint32_t)(uint16_t)f2bf_s(fmaxf(hacc[m][1] + b4.y, 0.f)) << 16);
                    const uint32_t hi = (uint32_t)(uint16_t)f2bf_s(fmaxf(hacc[m][2] + b4.z, 0.f))
                                      | ((uint32_t)(uint16_t)f2bf_s(fmaxf(hacc[m][3] + b4.w, 0.f)) << 16);
                    const int sl = (2 * (4 * w + m) + (g >> 1)) ^ (nb & 7);
                    *(uint2*)((char*)&s_h2[16 * pt + nb][0] + sl * 16 + 8 * (g & 1)) = make_uint2(lo, hi);
                }
            }

            // vrel = v + rel' + q for point w (pnw held — no aidx re-gather)
            {
                const bf16x8 rl0 = *(const bf16x8*)&s_rel[w][nb][8 * g];
                const bf16x8 rl1 = *(const bf16x8*)&s_rel[w][nb][32 + 8 * g];
                bf16x8 va, vb;
#pragma unroll
                for (int j = 0; j < 8; ++j) {
                    va[j] = f2bf_s(bf2f((uint16_t)pv0[j]) + bf2f((uint16_t)rl0[j]) + bf2f((uint16_t)pq0[j]));
                    vb[j] = f2bf_s(bf2f((uint16_t)pv1[j]) + bf2f((uint16_t)rl1[j]) + bf2f((uint16_t)pq1[j]));
                }
                *(bf16x8*)&s_vrel[16 * w + nb][8 * g]      = va;
                *(bf16x8*)&s_vrel[16 * w + nb][32 + 8 * g] = vb;
            }
        }
        __syncthreads();   // barrier-2

        // ================= P3: stage next group, scores+softmax+agg ==========
        stage_load(gb + gridDim.x);

#pragma unroll
        for (int mt = 0; mt < 4; ++mt) {
            const int ip  = i0 + mt;
            const int ipc = min(ip, npts - 1);

            f32x4 wacc = {0.f, 0.f, 0.f, 0.f};
            __builtin_amdgcn_s_setprio(1);
#pragma unroll
            for (int kt = 0; kt < 8; ++kt) {
                const int sl = (4 * kt + g) ^ (nb & 7);
                const bf16x8 a = *(const bf16x8*)((const char*)&s_h2[16 * mt + nb][0] + sl * 16);
                wacc = __builtin_amdgcn_mfma_f32_16x16x32_bf16(a, aw2[kt], wacc, 0, 0, 0);
            }
            __builtin_amdgcn_s_setprio(0);

            const uchar4 m4 = *(const uchar4*)(mask + (size_t)ipc * KNB + 4 * g);
            const float sc0 = m4.x ? -INFINITY : wacc[0];
            const float sc1 = m4.y ? -INFINITY : wacc[1];
            const float sc2 = m4.z ? -INFINITY : wacc[2];
            const float sc3 = m4.w ? -INFINITY : wacc[3];
            float mx = fmaxf(fmaxf(sc0, sc1), fmaxf(sc2, sc3));
            mx = fmaxf(mx, __shfl_xor(mx, 16));
            mx = fmaxf(mx, __shfl_xor(mx, 32));
            const float e0 = __expf(sc0 - mx), e1 = __expf(sc1 - mx);
            const float e2 = __expf(sc2 - mx), e3 = __expf(sc3 - mx);
            float den = (e0 + e1) + (e2 + e3);

            const int vc = 16 * w + nb;
            const float vr0 = bf2f(s_vrel[16 * mt + 4 * g + 0][vc]);
            const float vr1 = bf2f(s_vrel[16 * mt + 4 * g + 1][vc]);
            const float vr2 = bf2f(s_vrel[16 * mt + 4 * g + 2][vc]);
            const float vr3 = bf2f(s_vrel[16 * mt + 4 * g + 3][vc]);
            float num = e0 * vr0;
            num = fmaf(e1, vr1, num);
            num = fmaf(e2, vr2, num);
            num = fmaf(e3, vr3, num);

            den += __shfl_xor(den, 16); den += __shfl_xor(den, 32);
            num += __shfl_xor(num, 16); num += __shfl_xor(num, 32);
            if (lane < 16 && ip < npts)
                out[(size_t)ip * 64 + vc] = __fdividef(num, den);
        }
        // no third barrier needed (see header comment)
    }
}

// ---------------------------------------------------------------------------
extern "C" void kernel_launch(void* const* d_in, const int* in_sizes, int n_in,
                              void* d_out, int out_size, void* d_ws, size_t ws_size,
                              hipStream_t stream) {
    const float*   x     = (const float*)d_in[0];
    const float*   pos   = (const float*)d_in[1];
    const int*     aidx  = (const int*)d_in[2];
    const uint8_t* mask  = (const uint8_t*)d_in[3];
    const float*   wqkv  = (const float*)d_in[4];
    const float*   pm_w1 = (const float*)d_in[5];
    const float*   pm_b1 = (const float*)d_in[6];
    const float*   pm_w2 = (const float*)d_in[7];
    const float*   pm_b2 = (const float*)d_in[8];
    const float*   am_w1 = (const float*)d_in[9];
    const float*   am_b1 = (const float*)d_in[10];
    const float*   am_w2 = (const float*)d_in[11];
    // am_b2 (d_in[12]) is constant over the softmax axis -> cancels, unused
    float* out = (float*)d_out;
    const int n = in_sizes[0] / DIM;

    uint8_t* ws = (uint8_t*)d_ws;
    uint16_t* qkvp = (uint16_t*)ws;                               // n*192 bf16
    uint16_t* w1p  = (uint16_t*)(ws + (size_t)n * QKVW * 2);      // 16384 bf16
    uint16_t* w2p  = w1p + 16384;                                 // 16384 bf16
    uint16_t* pw2p = w2p + 16384;                                 // 4096 bf16

    const int nqkvb = (n + 15) / 16;
    prep_kernel<<<nqkvb + 144, 256, 0, stream>>>(x, wqkv, am_w1, am_w2, pm_w2,
                                                 qkvp, w1p, w2p, pw2p, n, nqkvb);
    ptl_main<<<512, 256, 0, stream>>>(pos, aidx, mask, pm_w1, pm_b1, pm_b2, am_b1,
                                      qkvp, w1p, w2p, pw2p, out, n);
}